// Round 6
// baseline (335.656 us; speedup 1.0000x reference)
//
#include <hip/hip_runtime.h>
#include <hip/hip_bf16.h>

#define NPAT 50000
#define NCON 20000
#define NN   70000
#define EE   800000
#define H    128

#define NCON_AL  20032                 // concepts padded to 64-alignment
#define SEGN     (NCON_AL + NPAT)      // 70032 segment ids
#define NBUCK    1095                  // ceil(SEGN/64)
#define RELSPLIT_B 313                 // buckets [0,313) = concept dsts (rel0)
#define BUCKCAP  5120                  // pairs capacity per bucket (max fill ~2900)
#define SUBS     16                    // sub-regions per bucket (reservation slots)
#define SUBCAP   (BUCKCAP / SUBS)      // 320 (max fill ~236)
#define BPE      4096                  // edges per binpack block
#define NBB      ((2 * EE + BPE - 1) / BPE)   // 391
#define CAP      4096                  // sorted-src capacity per bucket (max ~2900)

#define BM 128
#define BK 8
#define PB_T 391                       // patient row tiles (128 rows each)
#define CB_T 157                       // concept row tiles

typedef __attribute__((ext_vector_type(8))) short bf16x8;
typedef __attribute__((ext_vector_type(4))) float f32x4;

__device__ inline unsigned short f2bf(float f) {
    unsigned u = __float_as_uint(f);
    unsigned r = (u + 0x7FFFu + ((u >> 16) & 1u)) >> 16;
    return (unsigned short)r;
}
__device__ inline float bf2f_lo(unsigned v) { return __uint_as_float(v << 16); }
__device__ inline float bf2f_hi(unsigned v) { return __uint_as_float(v & 0xFFFF0000u); }

// ============ init: per-(bucket,sub) cursors at static bases ============
__global__ void init_gcur_kernel(int* __restrict__ gcur) {
    int j = blockIdx.x * 256 + threadIdx.x;
    if (j < NBUCK * SUBS) gcur[j] = (j >> 4) * BUCKCAP + (j & (SUBS - 1)) * SUBCAP;
}

// ============ binpack: 512 thr, LDS counting sort by bucket, run-reserve, write ====
__global__ __launch_bounds__(512) void binpack_kernel(
        const int* __restrict__ dst_pc, const int* __restrict__ src_pc,
        const int* __restrict__ dst_cp, const int* __restrict__ src_cp,
        int* __restrict__ gcur, unsigned* __restrict__ pairs) {
    __shared__ unsigned sval[BPE];           // 16 KB
    __shared__ unsigned short sbkt[BPE];     // 8 KB (bucket id per sorted slot)
    __shared__ int cnt[NBUCK];               // 4.4 KB (then local cursor)
    __shared__ int delta[NBUCK];             // 4.4 KB
    __shared__ int wtot[8];
    int t = threadIdx.x, blk = blockIdx.x;
    int base = blk * BPE;
    int n = min(BPE, 2 * EE - base);

    for (int i = t; i < NBUCK; i += 512) cnt[i] = 0;
    __syncthreads();

    unsigned pay[8];
    int bkt[8];
#pragma unroll
    for (int q = 0; q < 8; q++) {
        int li = q * 512 + t;
        bkt[q] = -1;
        if (li < n) {
            int i = base + li;
            int seg, src;
            if (i < EE) { seg = dst_pc[i];                src = src_pc[i]; }
            else        { seg = NCON_AL + dst_cp[i - EE]; src = src_cp[i - EE]; }
            int b = seg >> 6;
            pay[q] = (unsigned)src | ((unsigned)(seg & 63) << 16);
            bkt[q] = b;
            atomicAdd(&cnt[b], 1);
        }
    }
    __syncthreads();

    const int PER = (NBUCK + 511) / 512;   // 3
    int beg = t * PER;
    int s = 0;
#pragma unroll
    for (int k = 0; k < PER; k++) { int i = beg + k; if (i < NBUCK) s += cnt[i]; }
    // per-wave inclusive scan + cross-wave combine (2 barriers)
    int lane = t & 63, w8 = t >> 6;
    int incl = s;
#pragma unroll
    for (int o = 1; o < 64; o <<= 1) {
        int u = __shfl_up(incl, o);
        if (lane >= o) incl += u;
    }
    if (lane == 63) wtot[w8] = incl;
    __syncthreads();
    if (t == 0) {
        int r0 = 0;
#pragma unroll
        for (int k = 0; k < 8; k++) { int tmp = wtot[k]; wtot[k] = r0; r0 += tmp; }
    }
    __syncthreads();
    int run = incl - s + wtot[w8];

    int sub = blk & (SUBS - 1);
    int prefk[PER];
#pragma unroll
    for (int k = 0; k < PER; k++) {
        int i = beg + k;
        if (i < NBUCK) {
            prefk[k] = run;
            int c = cnt[i];
            if (c > 0) {
                int gb = atomicAdd(&gcur[i * SUBS + sub], c);
                delta[i] = gb - run;
            }
            run += c;
        }
    }
    __syncthreads();
#pragma unroll
    for (int k = 0; k < PER; k++) { int i = beg + k; if (i < NBUCK) cnt[i] = prefk[k]; }
    __syncthreads();

#pragma unroll
    for (int q = 0; q < 8; q++) {
        if (bkt[q] >= 0) {
            int b = bkt[q];
            int pos = atomicAdd(&cnt[b], 1);
            sval[pos] = pay[q];
            sbkt[pos] = (unsigned short)b;
        }
    }
    __syncthreads();
    for (int i = t; i < n; i += 512)
        pairs[delta[sbkt[i]] + i] = sval[i];
}

// ============ build CSR per bucket (runs ONCE): count + scan + place, dump ========
// ssrc dump overwrites the bucket's own pairs region (reads all done pre-barrier).
__global__ __launch_bounds__(512) void build_ssrc_kernel(
        const unsigned* __restrict__ pairs, const int* __restrict__ gcur,
        int* __restrict__ soffg) {
    __shared__ int cnt64[64];
    __shared__ int soff[65];
    __shared__ int scur[64];
    __shared__ unsigned short ssrc[CAP];
    int t = threadIdx.x, b = blockIdx.x;
    if (t < 64) cnt64[t] = 0;
    __syncthreads();
    // pass A: count per-seg degree over the 16 sub-regions
    for (int s = 0; s < SUBS; s++) {
        int rbase = b * BUCKCAP + s * SUBCAP;
        int rcnt = gcur[b * SUBS + s] - rbase;
        for (int i = t; i < rcnt; i += 512)
            atomicAdd(&cnt64[pairs[rbase + i] >> 16], 1);
    }
    __syncthreads();
    if (t < 64) {  // wave 0: exclusive scan
        int v = cnt64[t];
        int s = v;
#pragma unroll
        for (int o = 1; o < 64; o <<= 1) {
            int u = __shfl_up(s, o);
            if (t >= o) s += u;
        }
        soff[t + 1] = s;
        if (t == 0) soff[0] = 0;
        scur[t] = s - v;
    }
    __syncthreads();
    // pass B: place srcs per-dst-contiguous
    for (int s = 0; s < SUBS; s++) {
        int rbase = b * BUCKCAP + s * SUBCAP;
        int rcnt = gcur[b * SUBS + s] - rbase;
        for (int i = t; i < rcnt; i += 512) {
            unsigned p = pairs[rbase + i];
            int pos = atomicAdd(&scur[p >> 16], 1);
            ssrc[pos] = (unsigned short)(p & 0xFFFF);
        }
    }
    __syncthreads();
    // dump: soff + sorted srcs (as uints) into this bucket's pairs region
    if (t < 65) soffg[b * 65 + t] = soff[t];
    int tot = soff[64];
    unsigned* sg = (unsigned*)(((unsigned short*)pairs) + (size_t)b * BUCKCAP * 2);
    const unsigned* sl = (const unsigned*)ssrc;
    for (int i = t; i < ((tot + 1) >> 1); i += 512) sg[i] = sl[i];
}

// ============ proj GEMM (fp32 VALU, 256 thr, proven round-2 form) ============
struct GemmJob {
    const float* A1;
    const float* B1;
    const float* bias; unsigned short* Cbf;
    int lda1, K1, M;
};

__global__ void gemm_dual_kernel(GemmJob j0, GemmJob j1, int nb0) {
    __shared__ float sA[BK][BM];
    __shared__ float sB[BK][H];
    bool first = (int)blockIdx.x < nb0;
    GemmJob j = first ? j0 : j1;
    int bm = (first ? blockIdx.x : blockIdx.x - nb0) * BM;
    int tid = threadIdx.x;
    int am = tid >> 1;
    int ak = (tid & 1) * 4;
    int bk = tid >> 5;
    int bn = (tid & 31) * 4;
    int ty = tid >> 4;
    int tx = tid & 15;
    float acc[8][8] = {};
    for (int k0 = 0; k0 < j.K1; k0 += BK) {
        int gm = bm + am; if (gm >= j.M) gm = j.M - 1;
        float4 av = *(const float4*)&j.A1[(size_t)gm * j.lda1 + k0 + ak];
        float4 bv = *(const float4*)&j.B1[(size_t)(k0 + bk) * H + bn];
        __syncthreads();
        sA[ak + 0][am] = av.x; sA[ak + 1][am] = av.y;
        sA[ak + 2][am] = av.z; sA[ak + 3][am] = av.w;
        *(float4*)&sB[bk][bn] = bv;
        __syncthreads();
#pragma unroll
        for (int k = 0; k < BK; k++) {
            float a[8], bb[8];
            *(float4*)&a[0] = *(const float4*)&sA[k][ty * 8];
            *(float4*)&a[4] = *(const float4*)&sA[k][ty * 8 + 4];
            *(float4*)&bb[0] = *(const float4*)&sB[k][tx * 4];
            *(float4*)&bb[4] = *(const float4*)&sB[k][64 + tx * 4];
#pragma unroll
            for (int i = 0; i < 8; i++)
#pragma unroll
                for (int jj = 0; jj < 8; jj++)
                    acc[i][jj] += a[i] * bb[jj];
        }
    }
    float bcol[8];
    *(float4*)&bcol[0] = *(const float4*)&j.bias[tx * 4];
    *(float4*)&bcol[4] = *(const float4*)&j.bias[64 + tx * 4];
#pragma unroll
    for (int i = 0; i < 8; i++) {
        int gr = bm + ty * 8 + i;
        if (gr < j.M) {
#pragma unroll
            for (int q = 0; q < 8; q++) {
                float v = acc[i][q] + bcol[q];
                int gc = (q < 4) ? (tx * 4 + q) : (64 + tx * 4 + q - 4);
                j.Cbf[(size_t)gr * H + gc] = f2bf(v);
            }
        }
    }
}

// ============ FUSED gather + layer GEMM: block = 128-row output tile ============
// Phase 1: gather this tile's 2 buckets into LDS aggT[128][136] (bf16, same
//          f2bf rounding as before -> numerics identical).
// Phase 2: MFMA C = [A1 | aggT] @ bf16([Broot; B2]) + bias, relu. A2 fragments
//          read directly from aggT (no aggn round-trip). Rows >= M hold LDS
//          garbage; their MFMA outputs are row-independent and discarded by
//          the gr < M guard.
#define ACC8(a0, a1, v) \
    a0.x += bf2f_lo((v).x); a0.y += bf2f_hi((v).x); \
    a0.z += bf2f_lo((v).y); a0.w += bf2f_hi((v).y); \
    a1.x += bf2f_lo((v).z); a1.y += bf2f_hi((v).z); \
    a1.z += bf2f_lo((v).w); a1.w += bf2f_hi((v).w);

__global__ __launch_bounds__(512) void gmf_kernel(
        const unsigned short* __restrict__ X,     // [NN][H] layer input bf16
        const unsigned short* __restrict__ ssrcg,
        const int* __restrict__ soffg,
        const float* __restrict__ Broot,          // [H][H] fp32 k-major
        const float* __restrict__ Brel0,
        const float* __restrict__ Brel1,
        const float* __restrict__ bias,
        float* __restrict__ Cf,                   // fp32 out (layer 1) or null
        unsigned short* __restrict__ Cbf) {       // bf16 out (layer 0) or null
    __shared__ union {
        struct { int soff[2][65]; unsigned short ssrc[2][CAP]; } g;   // 16.9 KB
        struct { unsigned short sA[128][40]; unsigned short sBT[128][40]; } m; // 20.5 KB
    } sm;
    __shared__ unsigned short aggT[128][136];     // 34.8 KB, 16B-aligned rows

    int t = threadIdx.x;
    int blk = blockIdx.x;
    bool isC = blk < CB_T;                        // concept tiles first (heavier)
    int tile = isC ? blk : blk - CB_T;
    int bm = tile * 128;
    int M = isC ? NCON : NPAT;
    int b0 = isC ? 2 * tile : RELSPLIT_B + 2 * tile;
    int rowbase = isC ? 0 : NPAT;                 // gather-source row offset
    const unsigned short* A1 = X + (size_t)(isC ? NPAT : 0) * H;
    const float* B2 = isC ? Brel0 : Brel1;
    size_t crow0 = (size_t)(isC ? NPAT : 0) * H;  // output row offset

    // ---- phase 1: gather 2 buckets into aggT ----
    int nb = isC ? min(2, RELSPLIT_B - b0) : 2;   // concept tile 156 -> nb=1
#pragma unroll
    for (int h = 0; h < 2; h++)
        if (t < 65) sm.g.soff[h][t] = (h < nb) ? soffg[(b0 + h) * 65 + t] : 0;
    __syncthreads();
    for (int h = 0; h < nb; h++) {
        int tot = sm.g.soff[h][64];
        const unsigned* sg = (const unsigned*)(ssrcg + (size_t)(b0 + h) * BUCKCAP * 2);
        unsigned* sl = (unsigned*)sm.g.ssrc[h];
        for (int i = t; i < ((tot + 1) >> 1); i += 512) sl[i] = sg[i];
    }
    __syncthreads();
    int wv = t >> 6, lane = t & 63;
    int g = lane >> 4;          // edge slot 0..3
    int q = lane & 15;          // uint4 index within 256B row
    const uint4* xw4 = (const uint4*)X;
    int seglim = isC ? NCON : SEGN;
    for (int h = 0; h < nb; h++) {
        int segbase = (b0 + h) * 64;
        const unsigned short* ss = sm.g.ssrc[h];
        for (int i = 0; i < 8; i++) {
            int d = wv * 8 + i;
            if (segbase + d >= seglim) continue;   // tail segs: garbage rows, discarded
            int beg = sm.g.soff[h][d], end = sm.g.soff[h][d + 1];
            float4 aA0 = {0.f, 0.f, 0.f, 0.f}, aA1 = {0.f, 0.f, 0.f, 0.f};
            float4 aB0 = {0.f, 0.f, 0.f, 0.f}, aB1 = {0.f, 0.f, 0.f, 0.f};
            int j = beg;
            for (; j + 7 < end; j += 8) {          // 8 edges, 2 indep uint4/lane
                int sA_ = ss[j + g];
                int sB_ = ss[j + 4 + g];
                uint4 vA = xw4[(size_t)(rowbase + sA_) * 16 + q];
                uint4 vB = xw4[(size_t)(rowbase + sB_) * 16 + q];
                ACC8(aA0, aA1, vA);
                ACC8(aB0, aB1, vB);
            }
            for (; j < end; j += 4) {              // tail rounds of up to 4 edges
                if (g < end - j) {
                    int s0 = ss[j + g];
                    uint4 v = xw4[(size_t)(rowbase + s0) * 16 + q];
                    ACC8(aA0, aA1, v);
                }
            }
            aA0.x += aB0.x; aA0.y += aB0.y; aA0.z += aB0.z; aA0.w += aB0.w;
            aA1.x += aB1.x; aA1.y += aB1.y; aA1.z += aB1.z; aA1.w += aB1.w;
            float r0 = aA0.x, r1 = aA0.y, r2 = aA0.z, r3 = aA0.w;
            float r4 = aA1.x, r5 = aA1.y, r6 = aA1.z, r7 = aA1.w;
            r0 += __shfl_xor(r0, 16); r1 += __shfl_xor(r1, 16);
            r2 += __shfl_xor(r2, 16); r3 += __shfl_xor(r3, 16);
            r4 += __shfl_xor(r4, 16); r5 += __shfl_xor(r5, 16);
            r6 += __shfl_xor(r6, 16); r7 += __shfl_xor(r7, 16);
            r0 += __shfl_xor(r0, 32); r1 += __shfl_xor(r1, 32);
            r2 += __shfl_xor(r2, 32); r3 += __shfl_xor(r3, 32);
            r4 += __shfl_xor(r4, 32); r5 += __shfl_xor(r5, 32);
            r6 += __shfl_xor(r6, 32); r7 += __shfl_xor(r7, 32);
            if (g == 0) {                          // lanes 0..15: write one row
                float inv = 1.0f / (float)max(end - beg, 1);
                uint4 o;
                o.x = (unsigned)f2bf(r0 * inv) | ((unsigned)f2bf(r1 * inv) << 16);
                o.y = (unsigned)f2bf(r2 * inv) | ((unsigned)f2bf(r3 * inv) << 16);
                o.z = (unsigned)f2bf(r4 * inv) | ((unsigned)f2bf(r5 * inv) << 16);
                o.w = (unsigned)f2bf(r6 * inv) | ((unsigned)f2bf(r7 * inv) << 16);
                *(uint4*)&aggT[h * 64 + d][8 * q] = o;   // zero-deg -> zeros (required)
            }
        }
    }
    __syncthreads();   // aggT complete; union may flip after next barrier

    // ---- phase 2: MFMA (8 waves, 128x128 tile, K=256) ----
    int wr = wv >> 1, wc = wv & 1;                // 4x2 wave grid: 32 rows x 64 cols
    int m16 = lane & 15, kg = lane >> 4;
    f32x4 acc[2][4];
#pragma unroll
    for (int mt = 0; mt < 2; mt++)
#pragma unroll
        for (int nt = 0; nt < 4; nt++) acc[mt][nt] = (f32x4){0.f, 0.f, 0.f, 0.f};

    int ar = t >> 2, ah = t & 3;
    int gmA = bm + ar; if (gmA >= M) gmA = M - 1;
    int bn = t & 127, bq = t >> 7;                // 0..3

#pragma unroll
    for (int kt = 0; kt < 8; kt++) {
        int k0 = kt * 32;
        uint4 av;
        if (kt < 4) av = *(const uint4*)(A1 + (size_t)gmA * H + k0 + ah * 8);
        const float* bsrc = (kt < 4) ? (Broot + (size_t)k0 * H)
                                     : (B2 + (size_t)(k0 - 128) * H);
        float bvals[8];
#pragma unroll
        for (int kk = 0; kk < 8; kk++) bvals[kk] = bsrc[(size_t)(bq * 8 + kk) * H + bn];
        __syncthreads();
        if (kt < 4) *(uint4*)&sm.m.sA[ar][ah * 8] = av;
#pragma unroll
        for (int kk = 0; kk < 8; kk++) sm.m.sBT[bn][bq * 8 + kk] = f2bf(bvals[kk]);
        __syncthreads();
        bf16x8 af[2], bfg[4];
#pragma unroll
        for (int mt = 0; mt < 2; mt++) {
            int row = wr * 32 + mt * 16 + m16;
            af[mt] = (kt < 4) ? *(bf16x8*)&sm.m.sA[row][kg * 8]
                              : *(bf16x8*)&aggT[row][(k0 - 128) + kg * 8];
        }
#pragma unroll
        for (int nt = 0; nt < 4; nt++)
            bfg[nt] = *(bf16x8*)&sm.m.sBT[wc * 64 + nt * 16 + m16][kg * 8];
#pragma unroll
        for (int mt = 0; mt < 2; mt++)
#pragma unroll
            for (int nt = 0; nt < 4; nt++)
                acc[mt][nt] = __builtin_amdgcn_mfma_f32_16x16x32_bf16(
                    af[mt], bfg[nt], acc[mt][nt], 0, 0, 0);
    }
    float bv[4];
#pragma unroll
    for (int nt = 0; nt < 4; nt++) bv[nt] = bias[wc * 64 + nt * 16 + m16];
#pragma unroll
    for (int mt = 0; mt < 2; mt++) {
        int gr0 = bm + wr * 32 + mt * 16 + kg * 4;
#pragma unroll
        for (int r = 0; r < 4; r++) {
            int gr = gr0 + r;
            if (gr < M) {
#pragma unroll
                for (int nt = 0; nt < 4; nt++) {
                    int gc = wc * 64 + nt * 16 + m16;
                    float v = fmaxf(acc[mt][nt][r] + bv[nt], 0.f);
                    if (Cf)  Cf[crow0 + (size_t)gr * H + gc] = v;
                    if (Cbf) Cbf[crow0 + (size_t)gr * H + gc] = f2bf(v);
                }
            }
        }
    }
}

// ============ launch ============

extern "C" void kernel_launch(void* const* d_in, const int* in_sizes, int n_in,
                              void* d_out, int out_size, void* d_ws, size_t ws_size,
                              hipStream_t stream) {
    const float* x_patient = (const float*)d_in[0];
    const float* x_concept = (const float*)d_in[1];
    const float* W_p       = (const float*)d_in[2];
    const float* b_p       = (const float*)d_in[3];
    const float* W_c       = (const float*)d_in[4];
    const float* b_c       = (const float*)d_in[5];
    const float* W_root    = (const float*)d_in[6];
    const float* b_root    = (const float*)d_in[7];
    const float* W_rel     = (const float*)d_in[8];
    const int*   src_pc    = (const int*)d_in[9];
    const int*   dst_pc    = (const int*)d_in[10];
    const int*   src_cp    = (const int*)d_in[11];
    const int*   dst_cp    = (const int*)d_in[12];
    float* out = (float*)d_out;

    char* w = (char*)d_ws;
    unsigned short* xbf  = (unsigned short*)w; w += (size_t)NN * H * 2;     // 17.9 MB
    unsigned short* xbf2 = (unsigned short*)w; w += (size_t)NN * H * 2;     // 17.9 MB (was aggn)
    int* gcur = (int*)w;            w += (size_t)NBUCK * SUBS * 4;          // 70 KB
    unsigned* pairs = (unsigned*)w; w += (size_t)NBUCK * BUCKCAP * 4;       // 22.4 MB
    int* soffg = (int*)w;           w += (size_t)NBUCK * 65 * 4;            // 285 KB

    init_gcur_kernel<<<(NBUCK * SUBS + 255) / 256, 256, 0, stream>>>(gcur);
    binpack_kernel<<<NBB, 512, 0, stream>>>(dst_pc, src_pc, dst_cp, src_cp, gcur, pairs);
    build_ssrc_kernel<<<NBUCK, 512, 0, stream>>>(pairs, gcur, soffg);
    const unsigned short* ssrcg = (const unsigned short*)pairs;  // build dumped here

    // projections -> xbf
    {
        GemmJob jp = { x_patient, W_p, b_p, xbf, 64, 64, NPAT };
        GemmJob jc = { x_concept, W_c, b_c, xbf + (size_t)NPAT * H, 128, 128, NCON };
        gemm_dual_kernel<<<PB_T + CB_T, 256, 0, stream>>>(jp, jc, PB_T);
    }

    for (int l = 0; l < 2; l++) {
        const unsigned short* X = l ? xbf2 : xbf;
        const float* Wroot_l = W_root + (size_t)l * H * H;
        const float* Wrel_l0 = W_rel + (size_t)(l * 2 + 0) * H * H;
        const float* Wrel_l1 = W_rel + (size_t)(l * 2 + 1) * H * H;
        const float* br = b_root + (size_t)l * H;
        gmf_kernel<<<CB_T + PB_T, 512, 0, stream>>>(
            X, ssrcg, soffg, Wroot_l, Wrel_l0, Wrel_l1, br,
            l ? out : nullptr, l ? nullptr : xbf2);
    }
}

// Round 7
// 322.054 us; speedup vs baseline: 1.0422x; 1.0422x over previous
//
#include <hip/hip_runtime.h>
#include <hip/hip_bf16.h>

#define NPAT 50000
#define NCON 20000
#define NN   70000
#define EE   800000
#define H    128

#define NCON_AL  20032                 // concepts padded to 64-alignment
#define SEGN     (NCON_AL + NPAT)      // 70032 segment ids
#define NBUCK    1095                  // ceil(SEGN/64)
#define RELSPLIT_B 313                 // buckets [0,313) = concept dsts (rel0)
#define BUCKCAP  5120                  // pairs capacity per bucket (max fill ~2900)
#define SUBS     16                    // sub-regions per bucket (reservation slots)
#define SUBCAP   (BUCKCAP / SUBS)      // 320 (max fill ~236)
#define BPE      4096                  // edges per binpack block
#define NBB      ((2 * EE + BPE - 1) / BPE)   // 391
#define CAP      4096                  // sorted-src capacity per bucket (max ~2900)

#define BM 128
#define BK 8
#define PB_T 391                       // patient row tiles
#define CB_T 157                       // concept row tiles
#define PPAIR_P 196                    // patient tile pairs (last has dummy)
#define PPAIR_C 79                     // concept tile pairs (last has dummy)

typedef __attribute__((ext_vector_type(8))) short bf16x8;
typedef __attribute__((ext_vector_type(4))) float f32x4;

__device__ inline unsigned short f2bf(float f) {
    unsigned u = __float_as_uint(f);
    unsigned r = (u + 0x7FFFu + ((u >> 16) & 1u)) >> 16;
    return (unsigned short)r;
}
__device__ inline float bf2f_lo(unsigned v) { return __uint_as_float(v << 16); }
__device__ inline float bf2f_hi(unsigned v) { return __uint_as_float(v & 0xFFFF0000u); }

struct GemmJob {
    const float* A1;
    const float* B1;
    const float* bias; unsigned short* Cbf;
    int lda1, K1, M;
};

// ============ fused binpack ∥ proj GEMM: block-role split, proven bodies ============
// blocks [0,NBB): binpack (512 thr, r5-proven). blocks [NBB,..): proj — TWO
// independent 128-row tiles per block, each on 256 thr running the r2-proven
// gemm_dual inner loop (paired within one job so K1/barrier-count is
// block-uniform; odd tile counts get a dummy tile bm>=M that writes nothing).
// gcur starts zeroed (hipMemsetAsync); static bases added in-kernel.
union BPSmem {
    struct {                                  // binpack role: ~32.8 KB
        unsigned sval[BPE];                   // 16 KB
        unsigned short sbkt[BPE];             // 8 KB
        int cnt[NBUCK];                       // 4.4 KB
        int delta[NBUCK];                     // 4.4 KB
        int wtot[8];
    } b;
    struct {                                  // proj role: 16 KB (2 halves)
        float sA[2][BK][BM];
        float sB[2][BK][H];
    } p;
};

__global__ __launch_bounds__(512) void binpack_proj_kernel(
        const int* __restrict__ dst_pc, const int* __restrict__ src_pc,
        const int* __restrict__ dst_cp, const int* __restrict__ src_cp,
        int* __restrict__ gcur, unsigned* __restrict__ pairs,
        GemmJob j0, GemmJob j1) {
    __shared__ BPSmem sm;
    int t = threadIdx.x, blk = blockIdx.x;

    if (blk >= NBB) {
        // ---------------- proj role (r2 gemm_dual body, 256 thr per tile) ----------
        int half = t >> 8;                    // which tile of the pair
        int tid = t & 255;
        int pb = blk - NBB;
        bool first = pb < PPAIR_P;
        GemmJob j = first ? j0 : j1;
        int ntiles = first ? PB_T : CB_T;
        int tile = first ? pb * 2 + half : (pb - PPAIR_P) * 2 + half;
        if (tile > ntiles) tile = ntiles;     // (not reachable; safety)
        int bm = tile * BM;                   // tile==ntiles -> bm>=M -> dummy
        int am = tid >> 1;
        int ak = (tid & 1) * 4;
        int bk = tid >> 5;
        int bn = (tid & 31) * 4;
        int ty = tid >> 4;
        int tx = tid & 15;
        float acc[8][8] = {};
        for (int k0 = 0; k0 < j.K1; k0 += BK) {
            int gm = bm + am; if (gm >= j.M) gm = j.M - 1;
            float4 av = *(const float4*)&j.A1[(size_t)gm * j.lda1 + k0 + ak];
            float4 bv = *(const float4*)&j.B1[(size_t)(k0 + bk) * H + bn];
            __syncthreads();
            sm.p.sA[half][ak + 0][am] = av.x; sm.p.sA[half][ak + 1][am] = av.y;
            sm.p.sA[half][ak + 2][am] = av.z; sm.p.sA[half][ak + 3][am] = av.w;
            *(float4*)&sm.p.sB[half][bk][bn] = bv;
            __syncthreads();
#pragma unroll
            for (int k = 0; k < BK; k++) {
                float a[8], bb[8];
                *(float4*)&a[0] = *(const float4*)&sm.p.sA[half][k][ty * 8];
                *(float4*)&a[4] = *(const float4*)&sm.p.sA[half][k][ty * 8 + 4];
                *(float4*)&bb[0] = *(const float4*)&sm.p.sB[half][k][tx * 4];
                *(float4*)&bb[4] = *(const float4*)&sm.p.sB[half][k][64 + tx * 4];
#pragma unroll
                for (int i = 0; i < 8; i++)
#pragma unroll
                    for (int jj = 0; jj < 8; jj++)
                        acc[i][jj] += a[i] * bb[jj];
            }
        }
        float bcol[8];
        *(float4*)&bcol[0] = *(const float4*)&j.bias[tx * 4];
        *(float4*)&bcol[4] = *(const float4*)&j.bias[64 + tx * 4];
#pragma unroll
        for (int i = 0; i < 8; i++) {
            int gr = bm + ty * 8 + i;
            if (gr < j.M) {
#pragma unroll
                for (int q = 0; q < 8; q++) {
                    float v = acc[i][q] + bcol[q];
                    int gc = (q < 4) ? (tx * 4 + q) : (64 + tx * 4 + q - 4);
                    j.Cbf[(size_t)gr * H + gc] = f2bf(v);
                }
            }
        }
        return;
    }

    // ---------------- binpack role (r5-proven body) ----------------
    int base = blk * BPE;
    int n = min(BPE, 2 * EE - base);

    for (int i = t; i < NBUCK; i += 512) sm.b.cnt[i] = 0;
    __syncthreads();

    unsigned pay[8];
    int bkt[8];
#pragma unroll
    for (int q = 0; q < 8; q++) {
        int li = q * 512 + t;
        bkt[q] = -1;
        if (li < n) {
            int i = base + li;
            int seg, src;
            if (i < EE) { seg = dst_pc[i];                src = src_pc[i]; }
            else        { seg = NCON_AL + dst_cp[i - EE]; src = src_cp[i - EE]; }
            int b = seg >> 6;
            pay[q] = (unsigned)src | ((unsigned)(seg & 63) << 16);
            bkt[q] = b;
            atomicAdd(&sm.b.cnt[b], 1);
        }
    }
    __syncthreads();

    const int PER = (NBUCK + 511) / 512;   // 3
    int beg = t * PER;
    int s = 0;
#pragma unroll
    for (int k = 0; k < PER; k++) { int i = beg + k; if (i < NBUCK) s += sm.b.cnt[i]; }
    // per-wave inclusive scan + cross-wave combine (2 barriers)
    int lane = t & 63, w8 = t >> 6;
    int incl = s;
#pragma unroll
    for (int o = 1; o < 64; o <<= 1) {
        int u = __shfl_up(incl, o);
        if (lane >= o) incl += u;
    }
    if (lane == 63) sm.b.wtot[w8] = incl;
    __syncthreads();
    if (t == 0) {
        int r0 = 0;
#pragma unroll
        for (int k = 0; k < 8; k++) { int tmp = sm.b.wtot[k]; sm.b.wtot[k] = r0; r0 += tmp; }
    }
    __syncthreads();
    int run = incl - s + sm.b.wtot[w8];

    int sub = blk & (SUBS - 1);
    int prefk[PER];
#pragma unroll
    for (int k = 0; k < PER; k++) {
        int i = beg + k;
        if (i < NBUCK) {
            prefk[k] = run;
            int c = sm.b.cnt[i];
            if (c > 0) {
                int gb = atomicAdd(&gcur[i * SUBS + sub], c);   // relative cursor
                sm.b.delta[i] = (i * BUCKCAP + sub * SUBCAP + gb) - run;
            }
            run += c;
        }
    }
    __syncthreads();
#pragma unroll
    for (int k = 0; k < PER; k++) { int i = beg + k; if (i < NBUCK) sm.b.cnt[i] = prefk[k]; }
    __syncthreads();

#pragma unroll
    for (int q = 0; q < 8; q++) {
        if (bkt[q] >= 0) {
            int b = bkt[q];
            int pos = atomicAdd(&sm.b.cnt[b], 1);
            sm.b.sval[pos] = pay[q];
            sm.b.sbkt[pos] = (unsigned short)b;
        }
    }
    __syncthreads();
    for (int i = t; i < n; i += 512)
        pairs[sm.b.delta[sm.b.sbkt[i]] + i] = sm.b.sval[i];
}

// ============ build CSR per bucket (runs ONCE): count + scan + place, dump ========
// gcur now holds per-(bucket,sub) fill COUNTS (relative cursors).
__global__ __launch_bounds__(512) void build_ssrc_kernel(
        const unsigned* __restrict__ pairs, const int* __restrict__ gcur,
        int* __restrict__ soffg) {
    __shared__ int cnt64[64];
    __shared__ int soff[65];
    __shared__ int scur[64];
    __shared__ unsigned short ssrc[CAP];
    int t = threadIdx.x, b = blockIdx.x;
    if (t < 64) cnt64[t] = 0;
    __syncthreads();
    // pass A: count per-seg degree over the 16 sub-regions
    for (int s = 0; s < SUBS; s++) {
        int rbase = b * BUCKCAP + s * SUBCAP;
        int rcnt = gcur[b * SUBS + s];
        for (int i = t; i < rcnt; i += 512)
            atomicAdd(&cnt64[pairs[rbase + i] >> 16], 1);
    }
    __syncthreads();
    if (t < 64) {  // wave 0: exclusive scan
        int v = cnt64[t];
        int s = v;
#pragma unroll
        for (int o = 1; o < 64; o <<= 1) {
            int u = __shfl_up(s, o);
            if (t >= o) s += u;
        }
        soff[t + 1] = s;
        if (t == 0) soff[0] = 0;
        scur[t] = s - v;
    }
    __syncthreads();
    // pass B: place srcs per-dst-contiguous
    for (int s = 0; s < SUBS; s++) {
        int rbase = b * BUCKCAP + s * SUBCAP;
        int rcnt = gcur[b * SUBS + s];
        for (int i = t; i < rcnt; i += 512) {
            unsigned p = pairs[rbase + i];
            int pos = atomicAdd(&scur[p >> 16], 1);
            ssrc[pos] = (unsigned short)(p & 0xFFFF);
        }
    }
    __syncthreads();
    // dump: soff + sorted srcs (as uints) into this bucket's pairs region
    if (t < 65) soffg[b * 65 + t] = soff[t];
    int tot = soff[64];
    unsigned* sg = (unsigned*)(((unsigned short*)pairs) + (size_t)b * BUCKCAP * 2);
    const unsigned* sl = (const unsigned*)ssrc;
    for (int i = t; i < ((tot + 1) >> 1); i += 512) sg[i] = sl[i];
}

// ============ mean aggregation gather: block per bucket, 512 thr (r2-proven) =======
#define ACC8(a0, a1, v) \
    a0.x += bf2f_lo((v).x); a0.y += bf2f_hi((v).x); \
    a0.z += bf2f_lo((v).y); a0.w += bf2f_hi((v).y); \
    a1.x += bf2f_lo((v).z); a1.y += bf2f_hi((v).z); \
    a1.z += bf2f_lo((v).w); a1.w += bf2f_hi((v).w);

__global__ __launch_bounds__(512) void gather_kernel(
        const unsigned short* __restrict__ xbf,
        const unsigned short* __restrict__ ssrcg,
        const int* __restrict__ soffg,
        unsigned short* __restrict__ aggn) {
    __shared__ int soff[65];
    __shared__ unsigned short ssrc[CAP];
    int t = threadIdx.x, b = blockIdx.x;
    if (t < 65) soff[t] = soffg[b * 65 + t];
    __syncthreads();
    int tot = soff[64];
    const unsigned* sg = (const unsigned*)(ssrcg + (size_t)b * BUCKCAP * 2);
    unsigned* sl = (unsigned*)ssrc;
    for (int i = t; i < ((tot + 1) >> 1); i += 512) sl[i] = sg[i];
    __syncthreads();
    // gather: 8 waves x 8 segs
    int wv = t >> 6, lane = t & 63;
    int g = lane >> 4;          // edge slot 0..3
    int q = lane & 15;          // uint4 index within row (16 B granule)
    int rowbase = (b < RELSPLIT_B) ? 0 : NPAT;
    int seglim  = (b < RELSPLIT_B) ? NCON : SEGN;
    const uint4* xw4 = (const uint4*)xbf;   // 16 x uint4 per row
    for (int i = 0; i < 8; i++) {
        int d = wv * 8 + i;
        int seg = b * 64 + d;
        if (seg >= seglim) continue;
        int beg = soff[d], end = soff[d + 1];
        float4 aA0 = {0.f, 0.f, 0.f, 0.f}, aA1 = {0.f, 0.f, 0.f, 0.f};
        float4 aB0 = {0.f, 0.f, 0.f, 0.f}, aB1 = {0.f, 0.f, 0.f, 0.f};
        int j = beg;
        for (; j + 7 < end; j += 8) {  // 8 edges via 2 independent uint4/lane
            int sA = ssrc[j + g];
            int sB = ssrc[j + 4 + g];
            uint4 vA = xw4[(size_t)(rowbase + sA) * 16 + q];
            uint4 vB = xw4[(size_t)(rowbase + sB) * 16 + q];
            ACC8(aA0, aA1, vA);
            ACC8(aB0, aB1, vB);
        }
        for (; j < end; j += 4) {      // tail: masked rounds of up to 4 edges
            if (g < end - j) {
                int s0 = ssrc[j + g];
                uint4 v = xw4[(size_t)(rowbase + s0) * 16 + q];
                ACC8(aA0, aA1, v);
            }
        }
        aA0.x += aB0.x; aA0.y += aB0.y; aA0.z += aB0.z; aA0.w += aB0.w;
        aA1.x += aB1.x; aA1.y += aB1.y; aA1.z += aB1.z; aA1.w += aB1.w;
        float r0 = aA0.x, r1 = aA0.y, r2 = aA0.z, r3 = aA0.w;
        float r4 = aA1.x, r5 = aA1.y, r6 = aA1.z, r7 = aA1.w;
        // reduce across the 4 edge-slots (lane bits 4 and 5)
        r0 += __shfl_xor(r0, 16); r1 += __shfl_xor(r1, 16);
        r2 += __shfl_xor(r2, 16); r3 += __shfl_xor(r3, 16);
        r4 += __shfl_xor(r4, 16); r5 += __shfl_xor(r5, 16);
        r6 += __shfl_xor(r6, 16); r7 += __shfl_xor(r7, 16);
        r0 += __shfl_xor(r0, 32); r1 += __shfl_xor(r1, 32);
        r2 += __shfl_xor(r2, 32); r3 += __shfl_xor(r3, 32);
        r4 += __shfl_xor(r4, 32); r5 += __shfl_xor(r5, 32);
        r6 += __shfl_xor(r6, 32); r7 += __shfl_xor(r7, 32);
        if (g == 0) {
            float inv = 1.0f / (float)max(end - beg, 1);
            uint4 o;
            o.x = (unsigned)f2bf(r0 * inv) | ((unsigned)f2bf(r1 * inv) << 16);
            o.y = (unsigned)f2bf(r2 * inv) | ((unsigned)f2bf(r3 * inv) << 16);
            o.z = (unsigned)f2bf(r4 * inv) | ((unsigned)f2bf(r5 * inv) << 16);
            o.w = (unsigned)f2bf(r6 * inv) | ((unsigned)f2bf(r7 * inv) << 16);
            *(uint4*)&aggn[(size_t)seg * H + 8 * q] = o;  // zero-deg segs write 0 (required)
        }
    }
}

// ============ layer GEMM (bf16 MFMA, r2-proven): C = [A1|A2]@bf16([B1;B2])+bias, relu
struct MJob {
    const unsigned short* A1;  // [M][H] bf16
    const unsigned short* A2;  // [M][H] bf16
    const float* B1;           // [H][H] fp32 k-major
    const float* B2;
    const float* bias;
    float* C;                  // fp32 or null
    unsigned short* Cbf;       // bf16 or null
    int M;
};

__global__ __launch_bounds__(256) void gemm_mfma_kernel(MJob j0, MJob j1, int nb0) {
    __shared__ unsigned short sA[128][40];   // [row][k] pad 32->40
    __shared__ unsigned short sBT[128][40];  // [col][k]
    bool first = (int)blockIdx.x < nb0;
    MJob J = first ? j0 : j1;
    int bm = (first ? (int)blockIdx.x : (int)blockIdx.x - nb0) * 128;
    int tid = threadIdx.x;
    int wv = tid >> 6, lane = tid & 63;
    int wr = wv >> 1, wc = wv & 1;
    int m16 = lane & 15, kg = lane >> 4;

    f32x4 acc[4][4];
#pragma unroll
    for (int a = 0; a < 4; a++)
#pragma unroll
        for (int c = 0; c < 4; c++) acc[a][c] = (f32x4){0.f, 0.f, 0.f, 0.f};

    int ar = tid >> 1, ah = tid & 1;
    int gmA = bm + ar; if (gmA >= J.M) gmA = J.M - 1;
    int bn = tid & 127, bk0 = tid >> 7;

#pragma unroll
    for (int kt = 0; kt < 8; kt++) {
        int k0 = kt * 32;
        const unsigned short* asrc = (k0 < 128)
            ? (J.A1 + (size_t)gmA * H + k0)
            : (J.A2 + (size_t)gmA * H + (k0 - 128));
        const uint4* a4 = (const uint4*)(asrc + ah * 16);
        uint4 av0 = a4[0], av1 = a4[1];
        const float* bsrc = (k0 < 128) ? (J.B1 + (size_t)k0 * H)
                                       : (J.B2 + (size_t)(k0 - 128) * H);
        float bvals[16];
#pragma unroll
        for (int kk = 0; kk < 16; kk++) bvals[kk] = bsrc[(size_t)(2 * kk + bk0) * H + bn];
        __syncthreads();
        { uint4* d4 = (uint4*)&sA[ar][ah * 16]; d4[0] = av0; d4[1] = av1; }
#pragma unroll
        for (int kk = 0; kk < 16; kk++) sBT[bn][2 * kk + bk0] = f2bf(bvals[kk]);
        __syncthreads();
        bf16x8 af[4], bfg[4];
#pragma unroll
        for (int mt = 0; mt < 4; mt++)
            af[mt] = *(bf16x8*)&sA[wr * 64 + mt * 16 + m16][kg * 8];
#pragma unroll
        for (int nt = 0; nt < 4; nt++)
            bfg[nt] = *(bf16x8*)&sBT[wc * 64 + nt * 16 + m16][kg * 8];
#pragma unroll
        for (int mt = 0; mt < 4; mt++)
#pragma unroll
            for (int nt = 0; nt < 4; nt++)
                acc[mt][nt] = __builtin_amdgcn_mfma_f32_16x16x32_bf16(
                    af[mt], bfg[nt], acc[mt][nt], 0, 0, 0);
    }
    float bv[4];
#pragma unroll
    for (int nt = 0; nt < 4; nt++) bv[nt] = J.bias[wc * 64 + nt * 16 + m16];
#pragma unroll
    for (int mt = 0; mt < 4; mt++) {
        int gr0 = bm + wr * 64 + mt * 16 + kg * 4;
#pragma unroll
        for (int r = 0; r < 4; r++) {
            int gr = gr0 + r;
            if (gr < J.M) {
#pragma unroll
                for (int nt = 0; nt < 4; nt++) {
                    int gc = wc * 64 + nt * 16 + m16;
                    float v = fmaxf(acc[mt][nt][r] + bv[nt], 0.f);
                    if (J.C)   J.C[(size_t)gr * H + gc] = v;
                    if (J.Cbf) J.Cbf[(size_t)gr * H + gc] = f2bf(v);
                }
            }
        }
    }
}

// ============ launch ============

extern "C" void kernel_launch(void* const* d_in, const int* in_sizes, int n_in,
                              void* d_out, int out_size, void* d_ws, size_t ws_size,
                              hipStream_t stream) {
    const float* x_patient = (const float*)d_in[0];
    const float* x_concept = (const float*)d_in[1];
    const float* W_p       = (const float*)d_in[2];
    const float* b_p       = (const float*)d_in[3];
    const float* W_c       = (const float*)d_in[4];
    const float* b_c       = (const float*)d_in[5];
    const float* W_root    = (const float*)d_in[6];
    const float* b_root    = (const float*)d_in[7];
    const float* W_rel     = (const float*)d_in[8];
    const int*   src_pc    = (const int*)d_in[9];
    const int*   dst_pc    = (const int*)d_in[10];
    const int*   src_cp    = (const int*)d_in[11];
    const int*   dst_cp    = (const int*)d_in[12];
    float* out = (float*)d_out;

    char* w = (char*)d_ws;
    unsigned short* xbf  = (unsigned short*)w; w += (size_t)NN * H * 2;     // 17.9 MB
    unsigned short* aggn = (unsigned short*)w; w += (size_t)SEGN * H * 2;   // 17.9 MB
    int* gcur = (int*)w;            w += (size_t)NBUCK * SUBS * 4;          // 70 KB
    unsigned* pairs = (unsigned*)w; w += (size_t)NBUCK * BUCKCAP * 4;       // 22.4 MB
    int* soffg = (int*)w;           w += (size_t)NBUCK * 65 * 4;            // 285 KB

    hipMemsetAsync(gcur, 0, (size_t)NBUCK * SUBS * 4, stream);

    // fused: binpack ∥ proj GEMM (data-independent roles, proven inner loops)
    {
        GemmJob jp = { x_patient, W_p, b_p, xbf, 64, 64, NPAT };
        GemmJob jc = { x_concept, W_c, b_c, xbf + (size_t)NPAT * H, 128, 128, NCON };
        binpack_proj_kernel<<<NBB + PPAIR_P + PPAIR_C, 512, 0, stream>>>(
            dst_pc, src_pc, dst_cp, src_cp, gcur, pairs, jp, jc);
    }
    build_ssrc_kernel<<<NBUCK, 512, 0, stream>>>(pairs, gcur, soffg);
    const unsigned short* ssrcg = (const unsigned short*)pairs;  // build dumped here

    for (int l = 0; l < 2; l++) {
        gather_kernel<<<NBUCK, 512, 0, stream>>>(xbf, ssrcg, soffg, aggn);
        const float* Wroot_l = W_root + (size_t)l * H * H;
        const float* Wrel_l0 = W_rel + (size_t)(l * 2 + 0) * H * H;
        const float* Wrel_l1 = W_rel + (size_t)(l * 2 + 1) * H * H;
        const float* br = b_root + (size_t)l * H;
        float* cp = (l == 1) ? out : nullptr;
        float* cc = (l == 1) ? out + (size_t)NPAT * H : nullptr;
        unsigned short* bp = (l == 0) ? xbf : nullptr;                       // in-place ok
        unsigned short* bc = (l == 0) ? xbf + (size_t)NPAT * H : nullptr;
        MJob jp = { xbf, aggn + (size_t)NCON_AL * H, Wroot_l, Wrel_l1, br,
                    cp, bp, NPAT };
        MJob jc = { xbf + (size_t)NPAT * H, aggn, Wroot_l, Wrel_l0, br,
                    cc, bc, NCON };
        gemm_mfma_kernel<<<PB_T + CB_T, 256, 0, stream>>>(jp, jc, PB_T);
    }
}

// Round 9
// 301.918 us; speedup vs baseline: 1.1117x; 1.0667x over previous
//
#include <hip/hip_runtime.h>
#include <hip/hip_bf16.h>

#define NPAT 50000
#define NCON 20000
#define NN   70000
#define EE   800000
#define H    128
#define HH   (H * H)

#define NCON_AL  20032                 // concepts padded to 64-alignment
#define SEGN     (NCON_AL + NPAT)      // 70032 segment ids
#define NBUCK    1095                  // ceil(SEGN/64)
#define RELSPLIT_B 313                 // buckets [0,313) = concept dsts (rel0)
#define BUCKCAP  5120                  // pairs capacity per bucket (max fill ~2900)
#define SUBS     16                    // sub-regions per bucket (reservation slots)
#define SUBCAP   (BUCKCAP / SUBS)      // 320 (max fill ~236)
#define BPE      4096                  // edges per binpack block
#define NBB      ((2 * EE + BPE - 1) / BPE)   // 391
#define CAP      4096                  // sorted-src capacity per bucket (max ~2900)

#define BM 128
#define BK 8
#define PB_T 391                       // patient row tiles
#define CB_T 157                       // concept row tiles
#define SLAB (128 * 32)                // shorts per kt-slab
#define MATW (4 * SLAB)                // shorts per prepped weight matrix

typedef __attribute__((ext_vector_type(8))) short bf16x8;
typedef __attribute__((ext_vector_type(4))) float f32x4;

__device__ inline unsigned short f2bf(float f) {
    unsigned u = __float_as_uint(f);
    unsigned r = (u + 0x7FFFu + ((u >> 16) & 1u)) >> 16;
    return (unsigned short)r;
}
__device__ inline float bf2f_lo(unsigned v) { return __uint_as_float(v << 16); }
__device__ inline float bf2f_hi(unsigned v) { return __uint_as_float(v & 0xFFFF0000u); }

// ============ prep: W[k][col] fp32 -> prepW[mat][kt][col][32] bf16 ============
// mat: 0=Wroot_l0 1=Wrel_l0r0 2=Wrel_l0r1 3=Wroot_l1 4=Wrel_l1r0 5=Wrel_l1r1
// Same f2bf rounding as the old in-kernel conversion -> bit-identical numerics.
__global__ __launch_bounds__(256) void prep_weights_kernel(
        const float* __restrict__ W_root, const float* __restrict__ W_rel,
        unsigned short* __restrict__ prepW) {
    __shared__ unsigned short sT[32][130];
    int t = threadIdx.x, blk = blockIdx.x;
    int m = blk >> 2, kt4 = blk & 3;
    const float* src = (m % 3 == 0)
        ? (W_root + (size_t)(m / 3) * HH)
        : (W_rel + (size_t)((m / 3) * 2 + (m % 3) - 1) * HH);
    int k0 = kt4 * 32;
    int row = t >> 3, col0 = (t & 7) * 16;       // coalesced fp32 load, 16/thread
    const float* sp = src + (size_t)(k0 + row) * H + col0;
#pragma unroll
    for (int i = 0; i < 16; i++) sT[row][col0 + i] = f2bf(sp[i]);
    __syncthreads();
    int col = t >> 1, koff = (t & 1) * 16;       // transpose out of LDS
    unsigned short* op = prepW + (size_t)m * MATW + kt4 * SLAB + col * 32 + koff;
    unsigned short tmp[16] __attribute__((aligned(16)));
#pragma unroll
    for (int i = 0; i < 16; i++) tmp[i] = sT[koff + i][col];
    *(uint4*)&op[0] = *(uint4*)&tmp[0];
    *(uint4*)&op[8] = *(uint4*)&tmp[8];
}

// ============ binpack: 512 thr, LDS counting sort by bucket, run-reserve, write ====
// gcur starts zeroed (memset); relative cursors, static bases added in-kernel.
__global__ __launch_bounds__(512) void binpack_kernel(
        const int* __restrict__ dst_pc, const int* __restrict__ src_pc,
        const int* __restrict__ dst_cp, const int* __restrict__ src_cp,
        int* __restrict__ gcur, unsigned* __restrict__ pairs) {
    __shared__ unsigned sval[BPE];           // 16 KB
    __shared__ unsigned short sbkt[BPE];     // 8 KB
    __shared__ int cnt[NBUCK];               // 4.4 KB (then local cursor)
    __shared__ int delta[NBUCK];             // 4.4 KB
    __shared__ int wtot[8];
    int t = threadIdx.x, blk = blockIdx.x;
    int base = blk * BPE;
    int n = min(BPE, 2 * EE - base);

    for (int i = t; i < NBUCK; i += 512) cnt[i] = 0;
    __syncthreads();

    unsigned pay[8];
    int bkt[8];
#pragma unroll
    for (int q = 0; q < 8; q++) {
        int li = q * 512 + t;
        bkt[q] = -1;
        if (li < n) {
            int i = base + li;
            int seg, src;
            if (i < EE) { seg = dst_pc[i];                src = src_pc[i]; }
            else        { seg = NCON_AL + dst_cp[i - EE]; src = src_cp[i - EE]; }
            int b = seg >> 6;
            pay[q] = (unsigned)src | ((unsigned)(seg & 63) << 16);
            bkt[q] = b;
            atomicAdd(&cnt[b], 1);
        }
    }
    __syncthreads();

    const int PER = (NBUCK + 511) / 512;   // 3
    int beg = t * PER;
    int s = 0;
#pragma unroll
    for (int k = 0; k < PER; k++) { int i = beg + k; if (i < NBUCK) s += cnt[i]; }
    // per-wave inclusive scan + cross-wave combine (2 barriers)
    int lane = t & 63, w8 = t >> 6;
    int incl = s;
#pragma unroll
    for (int o = 1; o < 64; o <<= 1) {
        int u = __shfl_up(incl, o);
        if (lane >= o) incl += u;
    }
    if (lane == 63) wtot[w8] = incl;
    __syncthreads();
    if (t == 0) {
        int r0 = 0;
#pragma unroll
        for (int k = 0; k < 8; k++) { int tmp = wtot[k]; wtot[k] = r0; r0 += tmp; }
    }
    __syncthreads();
    int run = incl - s + wtot[w8];

    int sub = blk & (SUBS - 1);
    int prefk[PER];
#pragma unroll
    for (int k = 0; k < PER; k++) {
        int i = beg + k;
        if (i < NBUCK) {
            prefk[k] = run;
            int c = cnt[i];
            if (c > 0) {
                int gb = atomicAdd(&gcur[i * SUBS + sub], c);   // relative cursor
                delta[i] = (i * BUCKCAP + sub * SUBCAP + gb) - run;
            }
            run += c;
        }
    }
    __syncthreads();
#pragma unroll
    for (int k = 0; k < PER; k++) { int i = beg + k; if (i < NBUCK) cnt[i] = prefk[k]; }
    __syncthreads();

#pragma unroll
    for (int q = 0; q < 8; q++) {
        if (bkt[q] >= 0) {
            int b = bkt[q];
            int pos = atomicAdd(&cnt[b], 1);
            sval[pos] = pay[q];
            sbkt[pos] = (unsigned short)b;
        }
    }
    __syncthreads();
    for (int i = t; i < n; i += 512)
        pairs[delta[sbkt[i]] + i] = sval[i];
}

// ============ build CSR per bucket (runs ONCE): count + scan + place, dump ========
// gcur holds per-(bucket,sub) fill COUNTS (relative cursors).
__global__ __launch_bounds__(512) void build_ssrc_kernel(
        const unsigned* __restrict__ pairs, const int* __restrict__ gcur,
        int* __restrict__ soffg) {
    __shared__ int cnt64[64];
    __shared__ int soff[65];
    __shared__ int scur[64];
    __shared__ unsigned short ssrc[CAP];
    int t = threadIdx.x, b = blockIdx.x;
    if (t < 64) cnt64[t] = 0;
    __syncthreads();
    // pass A: count per-seg degree over the 16 sub-regions
    for (int s = 0; s < SUBS; s++) {
        int rbase = b * BUCKCAP + s * SUBCAP;
        int rcnt = gcur[b * SUBS + s];
        for (int i = t; i < rcnt; i += 512)
            atomicAdd(&cnt64[pairs[rbase + i] >> 16], 1);
    }
    __syncthreads();
    if (t < 64) {  // wave 0: exclusive scan
        int v = cnt64[t];
        int s = v;
#pragma unroll
        for (int o = 1; o < 64; o <<= 1) {
            int u = __shfl_up(s, o);
            if (t >= o) s += u;
        }
        soff[t + 1] = s;
        if (t == 0) soff[0] = 0;
        scur[t] = s - v;
    }
    __syncthreads();
    // pass B: place srcs per-dst-contiguous
    for (int s = 0; s < SUBS; s++) {
        int rbase = b * BUCKCAP + s * SUBCAP;
        int rcnt = gcur[b * SUBS + s];
        for (int i = t; i < rcnt; i += 512) {
            unsigned p = pairs[rbase + i];
            int pos = atomicAdd(&scur[p >> 16], 1);
            ssrc[pos] = (unsigned short)(p & 0xFFFF);
        }
    }
    __syncthreads();
    // dump: soff + sorted srcs (as uints) into this bucket's pairs region
    if (t < 65) soffg[b * 65 + t] = soff[t];
    int tot = soff[64];
    unsigned* sg = (unsigned*)(((unsigned short*)pairs) + (size_t)b * BUCKCAP * 2);
    const unsigned* sl = (const unsigned*)ssrc;
    for (int i = t; i < ((tot + 1) >> 1); i += 512) sg[i] = sl[i];
}

// ============ proj GEMM (fp32 VALU, 256 thr, r2-proven) ============
struct GemmJob {
    const float* A1;
    const float* B1;
    const float* bias; unsigned short* Cbf;
    int lda1, K1, M;
};

__global__ void gemm_dual_kernel(GemmJob j0, GemmJob j1, int nb0) {
    __shared__ float sA[BK][BM];
    __shared__ float sB[BK][H];
    bool first = (int)blockIdx.x < nb0;
    GemmJob j = first ? j0 : j1;
    int bm = (first ? blockIdx.x : blockIdx.x - nb0) * BM;
    int tid = threadIdx.x;
    int am = tid >> 1;
    int ak = (tid & 1) * 4;
    int bk = tid >> 5;
    int bn = (tid & 31) * 4;
    int ty = tid >> 4;
    int tx = tid & 15;
    float acc[8][8] = {};
    for (int k0 = 0; k0 < j.K1; k0 += BK) {
        int gm = bm + am; if (gm >= j.M) gm = j.M - 1;
        float4 av = *(const float4*)&j.A1[(size_t)gm * j.lda1 + k0 + ak];
        float4 bv = *(const float4*)&j.B1[(size_t)(k0 + bk) * H + bn];
        __syncthreads();
        sA[ak + 0][am] = av.x; sA[ak + 1][am] = av.y;
        sA[ak + 2][am] = av.z; sA[ak + 3][am] = av.w;
        *(float4*)&sB[bk][bn] = bv;
        __syncthreads();
#pragma unroll
        for (int k = 0; k < BK; k++) {
            float a[8], bb[8];
            *(float4*)&a[0] = *(const float4*)&sA[k][ty * 8];
            *(float4*)&a[4] = *(const float4*)&sA[k][ty * 8 + 4];
            *(float4*)&bb[0] = *(const float4*)&sB[k][tx * 4];
            *(float4*)&bb[4] = *(const float4*)&sB[k][64 + tx * 4];
#pragma unroll
            for (int i = 0; i < 8; i++)
#pragma unroll
                for (int jj = 0; jj < 8; jj++)
                    acc[i][jj] += a[i] * bb[jj];
        }
    }
    float bcol[8];
    *(float4*)&bcol[0] = *(const float4*)&j.bias[tx * 4];
    *(float4*)&bcol[4] = *(const float4*)&j.bias[64 + tx * 4];
#pragma unroll
    for (int i = 0; i < 8; i++) {
        int gr = bm + ty * 8 + i;
        if (gr < j.M) {
#pragma unroll
            for (int q = 0; q < 8; q++) {
                float v = acc[i][q] + bcol[q];
                int gc = (q < 4) ? (tx * 4 + q) : (64 + tx * 4 + q - 4);
                j.Cbf[(size_t)gr * H + gc] = f2bf(v);
            }
        }
    }
}

// ============ mean aggregation gather: block per bucket, 512 thr (r2-proven) =======
#define ACC8(a0, a1, v) \
    a0.x += bf2f_lo((v).x); a0.y += bf2f_hi((v).x); \
    a0.z += bf2f_lo((v).y); a0.w += bf2f_hi((v).y); \
    a1.x += bf2f_lo((v).z); a1.y += bf2f_hi((v).z); \
    a1.z += bf2f_lo((v).w); a1.w += bf2f_hi((v).w);

__global__ __launch_bounds__(512) void gather_kernel(
        const unsigned short* __restrict__ xbf,
        const unsigned short* __restrict__ ssrcg,
        const int* __restrict__ soffg,
        unsigned short* __restrict__ aggn) {
    __shared__ int soff[65];
    __shared__ unsigned short ssrc[CAP];
    int t = threadIdx.x, b = blockIdx.x;
    if (t < 65) soff[t] = soffg[b * 65 + t];
    __syncthreads();
    int tot = soff[64];
    const unsigned* sg = (const unsigned*)(ssrcg + (size_t)b * BUCKCAP * 2);
    unsigned* sl = (unsigned*)ssrc;
    for (int i = t; i < ((tot + 1) >> 1); i += 512) sl[i] = sg[i];
    __syncthreads();
    // gather: 8 waves x 8 segs
    int wv = t >> 6, lane = t & 63;
    int g = lane >> 4;          // edge slot 0..3
    int q = lane & 15;          // uint4 index within row (16 B granule)
    int rowbase = (b < RELSPLIT_B) ? 0 : NPAT;
    int seglim  = (b < RELSPLIT_B) ? NCON : SEGN;
    const uint4* xw4 = (const uint4*)xbf;   // 16 x uint4 per row
    for (int i = 0; i < 8; i++) {
        int d = wv * 8 + i;
        int seg = b * 64 + d;
        if (seg >= seglim) continue;
        int beg = soff[d], end = soff[d + 1];
        float4 aA0 = {0.f, 0.f, 0.f, 0.f}, aA1 = {0.f, 0.f, 0.f, 0.f};
        float4 aB0 = {0.f, 0.f, 0.f, 0.f}, aB1 = {0.f, 0.f, 0.f, 0.f};
        int j = beg;
        for (; j + 7 < end; j += 8) {  // 8 edges via 2 independent uint4/lane
            int sA = ssrc[j + g];
            int sB = ssrc[j + 4 + g];
            uint4 vA = xw4[(size_t)(rowbase + sA) * 16 + q];
            uint4 vB = xw4[(size_t)(rowbase + sB) * 16 + q];
            ACC8(aA0, aA1, vA);
            ACC8(aB0, aB1, vB);
        }
        for (; j < end; j += 4) {      // tail: masked rounds of up to 4 edges
            if (g < end - j) {
                int s0 = ssrc[j + g];
                uint4 v = xw4[(size_t)(rowbase + s0) * 16 + q];
                ACC8(aA0, aA1, v);
            }
        }
        aA0.x += aB0.x; aA0.y += aB0.y; aA0.z += aB0.z; aA0.w += aB0.w;
        aA1.x += aB1.x; aA1.y += aB1.y; aA1.z += aB1.z; aA1.w += aB1.w;
        float r0 = aA0.x, r1 = aA0.y, r2 = aA0.z, r3 = aA0.w;
        float r4 = aA1.x, r5 = aA1.y, r6 = aA1.z, r7 = aA1.w;
        // reduce across the 4 edge-slots (lane bits 4 and 5)
        r0 += __shfl_xor(r0, 16); r1 += __shfl_xor(r1, 16);
        r2 += __shfl_xor(r2, 16); r3 += __shfl_xor(r3, 16);
        r4 += __shfl_xor(r4, 16); r5 += __shfl_xor(r5, 16);
        r6 += __shfl_xor(r6, 16); r7 += __shfl_xor(r7, 16);
        r0 += __shfl_xor(r0, 32); r1 += __shfl_xor(r1, 32);
        r2 += __shfl_xor(r2, 32); r3 += __shfl_xor(r3, 32);
        r4 += __shfl_xor(r4, 32); r5 += __shfl_xor(r5, 32);
        r6 += __shfl_xor(r6, 32); r7 += __shfl_xor(r7, 32);
        if (g == 0) {
            float inv = 1.0f / (float)max(end - beg, 1);
            uint4 o;
            o.x = (unsigned)f2bf(r0 * inv) | ((unsigned)f2bf(r1 * inv) << 16);
            o.y = (unsigned)f2bf(r2 * inv) | ((unsigned)f2bf(r3 * inv) << 16);
            o.z = (unsigned)f2bf(r4 * inv) | ((unsigned)f2bf(r5 * inv) << 16);
            o.w = (unsigned)f2bf(r6 * inv) | ((unsigned)f2bf(r7 * inv) << 16);
            *(uint4*)&aggn[(size_t)seg * H + 8 * q] = o;  // zero-deg segs write 0 (required)
        }
    }
}

// ============ layer GEMM (bf16 MFMA): C = [A1|A2] @ [BT1;BT2] + bias, relu ======
// B operands come PRE-CONVERTED from prep_weights_kernel as bf16 kt-slabs
// [4][128][32]; staging is two coalesced uint4 loads per thread per K-step
// (replaces 16 scalar fp32 loads + 16 f2bf). Everything else r2-proven.
struct MJob {
    const unsigned short* A1;  // [M][H] bf16
    const unsigned short* A2;  // [M][H] bf16
    const unsigned short* BT1; // [4][128][32] bf16 slabs (k 0..127)
    const unsigned short* BT2; // [4][128][32] bf16 slabs (k 128..255)
    const float* bias;
    float* C;                  // fp32 or null
    unsigned short* Cbf;       // bf16 or null
    int M;
};

__global__ __launch_bounds__(256) void gemm_mfma_kernel(MJob j0, MJob j1, int nb0) {
    __shared__ unsigned short sA[128][40];   // [row][k] pad 32->40
    __shared__ unsigned short sBT[128][40];  // [col][k]
    bool first = (int)blockIdx.x < nb0;
    MJob J = first ? j0 : j1;
    int bm = (first ? (int)blockIdx.x : (int)blockIdx.x - nb0) * 128;
    int tid = threadIdx.x;
    int wv = tid >> 6, lane = tid & 63;
    int wr = wv >> 1, wc = wv & 1;
    int m16 = lane & 15, kg = lane >> 4;

    f32x4 acc[4][4];
#pragma unroll
    for (int a = 0; a < 4; a++)
#pragma unroll
        for (int c = 0; c < 4; c++) acc[a][c] = (f32x4){0.f, 0.f, 0.f, 0.f};

    int ar = tid >> 1, ah = tid & 1;
    int gmA = bm + ar; if (gmA >= J.M) gmA = J.M - 1;
    int bcol = tid >> 1, bko = (tid & 1) * 16;   // B staging: col, k-chunk

#pragma unroll
    for (int kt = 0; kt < 8; kt++) {
        int k0 = kt * 32;
        const unsigned short* asrc = (k0 < 128)
            ? (J.A1 + (size_t)gmA * H + k0)
            : (J.A2 + (size_t)gmA * H + (k0 - 128));
        const uint4* a4 = (const uint4*)(asrc + ah * 16);
        uint4 av0 = a4[0], av1 = a4[1];
        const unsigned short* slab = (kt < 4) ? (J.BT1 + kt * SLAB)
                                              : (J.BT2 + (kt - 4) * SLAB);
        const uint4* b4 = (const uint4*)(slab + tid * 16);   // coalesced 32B
        uint4 bv0 = b4[0], bv1 = b4[1];
        __syncthreads();
        { uint4* d4 = (uint4*)&sA[ar][ah * 16]; d4[0] = av0; d4[1] = av1; }
        { uint4* d4 = (uint4*)&sBT[bcol][bko]; d4[0] = bv0; d4[1] = bv1; }
        __syncthreads();
        bf16x8 af[4], bfg[4];
#pragma unroll
        for (int mt = 0; mt < 4; mt++)
            af[mt] = *(bf16x8*)&sA[wr * 64 + mt * 16 + m16][kg * 8];
#pragma unroll
        for (int nt = 0; nt < 4; nt++)
            bfg[nt] = *(bf16x8*)&sBT[wc * 64 + nt * 16 + m16][kg * 8];
#pragma unroll
        for (int mt = 0; mt < 4; mt++)
#pragma unroll
            for (int nt = 0; nt < 4; nt++)
                acc[mt][nt] = __builtin_amdgcn_mfma_f32_16x16x32_bf16(
                    af[mt], bfg[nt], acc[mt][nt], 0, 0, 0);
    }
    float bv[4];
#pragma unroll
    for (int nt = 0; nt < 4; nt++) bv[nt] = J.bias[wc * 64 + nt * 16 + m16];
#pragma unroll
    for (int mt = 0; mt < 4; mt++) {
        int gr0 = bm + wr * 64 + mt * 16 + kg * 4;
#pragma unroll
        for (int r = 0; r < 4; r++) {
            int gr = gr0 + r;
            if (gr < J.M) {
#pragma unroll
                for (int nt = 0; nt < 4; nt++) {
                    int gc = wc * 64 + nt * 16 + m16;
                    float v = fmaxf(acc[mt][nt][r] + bv[nt], 0.f);
                    if (J.C)   J.C[(size_t)gr * H + gc] = v;
                    if (J.Cbf) J.Cbf[(size_t)gr * H + gc] = f2bf(v);
                }
            }
        }
    }
}

// ============ launch ============

static inline size_t align256(size_t x) { return (x + 255) & ~(size_t)255; }

extern "C" void kernel_launch(void* const* d_in, const int* in_sizes, int n_in,
                              void* d_out, int out_size, void* d_ws, size_t ws_size,
                              hipStream_t stream) {
    const float* x_patient = (const float*)d_in[0];
    const float* x_concept = (const float*)d_in[1];
    const float* W_p       = (const float*)d_in[2];
    const float* b_p       = (const float*)d_in[3];
    const float* W_c       = (const float*)d_in[4];
    const float* b_c       = (const float*)d_in[5];
    const float* W_root    = (const float*)d_in[6];
    const float* b_root    = (const float*)d_in[7];
    const float* W_rel     = (const float*)d_in[8];
    const int*   src_pc    = (const int*)d_in[9];
    const int*   dst_pc    = (const int*)d_in[10];
    const int*   src_cp    = (const int*)d_in[11];
    const int*   dst_cp    = (const int*)d_in[12];
    float* out = (float*)d_out;

    // every carve 256B-aligned (r8 bug: soffg size 284,700 left prepW at a
    // 4-mod-16 address -> misaligned uint4 accesses -> GPU fault)
    char* w = (char*)d_ws;
    unsigned short* xbf  = (unsigned short*)w; w += align256((size_t)NN * H * 2);
    unsigned short* aggn = (unsigned short*)w; w += align256((size_t)SEGN * H * 2);
    int* gcur = (int*)w;            w += align256((size_t)NBUCK * SUBS * 4);
    unsigned* pairs = (unsigned*)w; w += align256((size_t)NBUCK * BUCKCAP * 4);
    int* soffg = (int*)w;           w += align256((size_t)NBUCK * 65 * 4);
    unsigned short* prepW = (unsigned short*)w; w += align256((size_t)6 * MATW * 2);

    hipMemsetAsync(gcur, 0, (size_t)NBUCK * SUBS * 4, stream);
    prep_weights_kernel<<<24, 256, 0, stream>>>(W_root, W_rel, prepW);
    binpack_kernel<<<NBB, 512, 0, stream>>>(dst_pc, src_pc, dst_cp, src_cp, gcur, pairs);
    build_ssrc_kernel<<<NBUCK, 512, 0, stream>>>(pairs, gcur, soffg);
    const unsigned short* ssrcg = (const unsigned short*)pairs;  // build dumped here

    // projections -> xbf
    {
        GemmJob jp = { x_patient, W_p, b_p, xbf, 64, 64, NPAT };
        GemmJob jc = { x_concept, W_c, b_c, xbf + (size_t)NPAT * H, 128, 128, NCON };
        gemm_dual_kernel<<<PB_T + CB_T, 256, 0, stream>>>(jp, jc, PB_T);
    }

    for (int l = 0; l < 2; l++) {
        gather_kernel<<<NBUCK, 512, 0, stream>>>(xbf, ssrcg, soffg, aggn);
        const unsigned short* BTroot = prepW + (size_t)(3 * l + 0) * MATW;
        const unsigned short* BTrel0 = prepW + (size_t)(3 * l + 1) * MATW;
        const unsigned short* BTrel1 = prepW + (size_t)(3 * l + 2) * MATW;
        const float* br = b_root + (size_t)l * H;
        float* cp = (l == 1) ? out : nullptr;
        float* cc = (l == 1) ? out + (size_t)NPAT * H : nullptr;
        unsigned short* bp = (l == 0) ? xbf : nullptr;                       // in-place ok
        unsigned short* bc = (l == 0) ? xbf + (size_t)NPAT * H : nullptr;
        MJob jp = { xbf, aggn + (size_t)NCON_AL * H, BTroot, BTrel1, br,
                    cp, bp, NPAT };
        MJob jc = { xbf + (size_t)NPAT * H, aggn, BTroot, BTrel0, br,
                    cc, bc, NCON };
        gemm_mfma_kernel<<<PB_T + CB_T, 256, 0, stream>>>(jp, jc, PB_T);
    }
}